// Round 4
// baseline (61.956 us; speedup 1.0000x reference)
//
#include <hip/hip_runtime.h>

#define NG 48
#define NC 16
#define NPTS (NG * NG * NG)
#define E2F 7.3890561f
#define NINE_OVER_E2 1.2180175f
#define LOG2E 1.44269504f

// brick: 2 x 2 x 16 grid points, one point per lane, 8 waves per block
#define W 8
#define SEGCAP 28     // per-wave candidate segment (expected ~6.4, P(>28) ~ 1e-10)

__device__ __constant__ float c_vdw[4] = {1.52f, 1.7f, 1.55f, 1.8f};

// ---- prep: pack per-atom data once ----
__global__ void prep_kernel(const float* __restrict__ coords,
                            const int* __restrict__ ch_idx,
                            const int* __restrict__ fg,
                            float4* __restrict__ atomA,
                            float4* __restrict__ atomB, int natoms)
{
    const int i = blockIdx.x * blockDim.x + threadIdx.x;
    if (i >= natoms) return;
    const float x = coords[3 * i + 0];
    const float y = coords[3 * i + 1];
    const float z = coords[3 * i + 2];
    const int ci = ch_idx[i];
    const int f  = fg[i];
    const float r  = c_vdw[ci];
    const float r2 = r * r;
    int c1 = (f == 14) ? 4 : ((f == 15) ? 6 : f + 4);
    if (f == 12 || f == 13) c1 = -1;
    const int c2 = (f == 14) ? 5 : ((f == 15) ? 9 : -1);
    int mask = 1 << ci;
    if (c1 >= 0) mask |= 1 << c1;
    if (c2 >= 0) mask |= 1 << c2;
    atomA[i] = make_float4(x, y, z, 1.5f * r);                       // w = cutoff
    atomB[i] = make_float4(-2.0f * LOG2E / r2,                       // exp2-folded
                           4.0f / (E2F * r2),
                           12.0f / (E2F * r),
                           __int_as_float(mask));
}

// ---- main: 8 waves, brick 2x2x16, LDS accumulator planes ----
__global__ __launch_bounds__(512, 8)
void density_kernel(const float4* __restrict__ atomA,
                    const float4* __restrict__ atomB,
                    float* __restrict__ out, int natoms)
{
    __shared__ float4 sA[W * SEGCAP];
    __shared__ float4 sB[W * SEGCAP];
    __shared__ float sAcc[W][NC][64];    // 32 KB wave-private accumulator planes
    __shared__ int sCnt[W];

    const int t = threadIdx.x;
    const int w = t >> 6;               // wave 0..7
    const int l = t & 63;
    const int bz = blockIdx.x, by = blockIdx.y, bx = blockIdx.z;

    // zero accumulator planes (covered by the barrier below)
    {
        float4* p = (float4*)sAcc;
        p[t]        = make_float4(0.f, 0.f, 0.f, 0.f);
        p[t + 512]  = make_float4(0.f, 0.f, 0.f, 0.f);
        p[t + 1024] = make_float4(0.f, 0.f, 0.f, 0.f);
        p[t + 1536] = make_float4(0.f, 0.f, 0.f, 0.f);
    }

    // brick point extents: x,y span 0.5; z spans 7.5
    const float blox = bx * 1.0f, bhix = blox + 0.5f;
    const float bloy = by * 1.0f, bhiy = bloy + 0.5f;
    const float bloz = bz * 8.0f, bhiz = bloz + 7.5f;

    // ---- wave-private scan of 1/8 of the atoms (4 iters), ballot-compaction ----
    const int chunk = (natoms + W - 1) / W;        // 256
    const int a0 = w * chunk;
    const int a1 = min(a0 + chunk, natoms);
    int cnt = 0;
    #pragma unroll 2
    for (int base = a0; base < a1; base += 64) {
        const int a = base + l;
        float4 pA;
        bool pred = false;
        if (a < a1) {
            pA = atomA[a];
            const float ddx = fmaxf(fmaxf(blox - pA.x, pA.x - bhix), 0.0f);
            const float ddy = fmaxf(fmaxf(bloy - pA.y, pA.y - bhiy), 0.0f);
            const float ddz = fmaxf(fmaxf(bloz - pA.z, pA.z - bhiz), 0.0f);
            pred = fmaf(ddx, ddx, fmaf(ddy, ddy, ddz * ddz)) < pA.w * pA.w;
        }
        const unsigned long long m = __ballot(pred);
        if (pred) {
            const int o = cnt + __popcll(m & ((1ull << l) - 1ull));
            if (o < SEGCAP) {
                sA[w * SEGCAP + o] = pA;
                sB[w * SEGCAP + o] = atomB[a];
            }
        }
        cnt += __popcll(m);
    }
    if (l == 0) sCnt[w] = (cnt > SEGCAP) ? SEGCAP : cnt;
    __syncthreads();

    // lane -> grid point
    const int tz = l & 15, ty = (l >> 4) & 1, tx = l >> 5;
    const float px = (bx * 2 + tx) * 0.5f;
    const float py = (by * 2 + ty) * 0.5f;
    const float pz = (bz * 16 + tz) * 0.5f;

    // ---- gather: rotated 1/8 share of each segment; <=3 ds_add_f32 per hit ----
    float* const accw = &sAcc[w][0][l];            // + c*64 indexes channel c
    for (int s = 0; s < W; ++s) {
        const int cs = sCnt[s];
        const int segbase = s * SEGCAP;
        for (int i = (w + s) & 7; i < cs; i += W) {
            const float4 A = sA[segbase + i];      // wave-uniform broadcast
            const float4 B = sB[segbase + i];
            const float dx = px - A.x;
            const float dy = py - A.y;
            const float dz = pz - A.z;
            const float d2 = fmaf(dx, dx, fmaf(dy, dy, dz * dz));
            const float cut2 = A.w * A.w;
            const float r2 = cut2 * (4.0f / 9.0f);
            const float d  = sqrtf(d2);
            const float f1 = exp2f(B.x * d2);      // single v_exp_f32
            const float f2 = fmaf(B.y, d2, fmaf(-B.z, d, NINE_OVER_E2));
            float val = (d2 < r2) ? f1 : f2;
            val = (d2 < cut2) ? val : 0.0f;        // branchless; +0.0 adds are exact
            int chan = __builtin_amdgcn_readfirstlane(__float_as_int(B.w));
            int c0 = __builtin_ctz(chan);
            atomicAdd(accw + c0 * 64, val);        // ds_add_f32, distinct lanes
            chan &= chan - 1;
            if (chan) {
                const int c1 = __builtin_ctz(chan);
                atomicAdd(accw + c1 * 64, val);
                chan &= chan - 1;
                if (chan) {
                    const int c2 = __builtin_ctz(chan);
                    atomicAdd(accw + c2 * 64, val);
                }
            }
        }
    }
    __syncthreads();

    // ---- reduce 8 planes + coalesced store (64B runs) ----
    #pragma unroll
    for (int j = 0; j < 2; ++j) {
        const int idx = t + j * 512;               // 0..1023 = (c, lane)
        const int c  = idx >> 6;
        const int ll = idx & 63;
        float sum = 0.0f;
        #pragma unroll
        for (int s = 0; s < W; ++s) sum += sAcc[s][c][ll];
        const int gz = bz * 16 + (ll & 15);
        const int gy = by * 2 + ((ll >> 4) & 1);
        const int gx = bx * 2 + (ll >> 5);
        out[c * NPTS + (gx * NG + gy) * NG + gz] = sum;
    }
}

extern "C" void kernel_launch(void* const* d_in, const int* in_sizes, int n_in,
                              void* d_out, int out_size, void* d_ws, size_t ws_size,
                              hipStream_t stream) {
    (void)n_in; (void)ws_size; (void)out_size;
    const float* coords = (const float*)d_in[0];
    const int* ch = (const int*)d_in[1];
    const int* fgp = (const int*)d_in[2];
    float* out = (float*)d_out;
    const int natoms = in_sizes[0] / 3;

    float4* atomA = (float4*)d_ws;
    float4* atomB = atomA + natoms;

    prep_kernel<<<(natoms + 255) / 256, 256, 0, stream>>>(coords, ch, fgp, atomA, atomB, natoms);
    dim3 grid(NG / 16, NG / 2, NG / 2);   // (3, 24, 24) = (bz, by, bx)
    density_kernel<<<grid, 512, 0, stream>>>(atomA, atomB, out, natoms);
}

// Round 5
// 21.500 us; speedup vs baseline: 2.8817x; 2.8817x over previous
//
#include <hip/hip_runtime.h>

#define NG 48
#define NC 16
#define NPTS (NG * NG * NG)
#define E2F 7.3890561f
#define NINE_OVER_E2 1.2180175f
#define LOG2E 1.44269504f

#define BR 4            // 4x4x4 grid-point brick per block
#define SEGCAP 48       // per-wave LDS candidate segment (expected ~6.4, +17 sigma)
#define SBCAP 512       // per-superblock candidate cap (expected ~320, +12 sigma)
#define MAXATOMS 2048

__device__ __constant__ float c_vdw[4] = {1.52f, 1.7f, 1.55f, 1.8f};

__device__ __forceinline__ void atom_params(int ci, int f, float r,
                                            float& b0, float& b1, float& b2, int& mask) {
    const float r2 = r * r;
    int c1 = (f == 14) ? 4 : ((f == 15) ? 6 : f + 4);
    if (f == 12 || f == 13) c1 = -1;
    const int c2 = (f == 14) ? 5 : ((f == 15) ? 9 : -1);
    mask = 1 << ci;
    if (c1 >= 0) mask |= 1 << c1;
    if (c2 >= 0) mask |= 1 << c2;
    b0 = -2.0f * LOG2E / r2;     // exp2-folded gaussian coef
    b1 = 4.0f / (E2F * r2);
    b2 = 12.0f / (E2F * r);
}

// ================= Kernel A: fused prep + per-superblock candidate build ==========
__global__ __launch_bounds__(1024)
void build_kernel(const float* __restrict__ coords,
                  const int* __restrict__ ch_idx,
                  const int* __restrict__ fg,
                  float4* __restrict__ segA, float4* __restrict__ segB,
                  int* __restrict__ counts, int natoms)
{
    __shared__ float sx[MAXATOMS], sy[MAXATOMS], sz[MAXATOMS], scut[MAXATOMS];
    __shared__ float sb0[MAXATOMS], sb1[MAXATOMS], sb2[MAXATOMS], sb3[MAXATOMS];
    __shared__ int sCnt[16];

    const int t = threadIdx.x, w = t >> 6, l = t & 63;
    const int n = min(natoms, MAXATOMS);

    for (int i = t; i < n; i += 1024) {
        const float x = coords[3 * i], y = coords[3 * i + 1], z = coords[3 * i + 2];
        const int ci = ch_idx[i], f = fg[i];
        const float r = c_vdw[ci];
        float b0, b1, b2; int mask;
        atom_params(ci, f, r, b0, b1, b2, mask);
        sx[i] = x; sy[i] = y; sz[i] = z; scut[i] = 1.5f * r;
        sb0[i] = b0; sb1[i] = b1; sb2[i] = b2; sb3[i] = __int_as_float(mask);
    }
    __syncthreads();

    const int sb = blockIdx.x;                       // 0..26
    const int sbx = sb / 9, sby = (sb / 3) % 3, sbz = sb % 3;
    const float lox = sbx * 8.0f, hix = lox + 7.5f;  // 16-point span
    const float loy = sby * 8.0f, hiy = loy + 7.5f;
    const float loz = sbz * 8.0f, hiz = loz + 7.5f;

    int runTot = 0;
    for (int base = 0; base < n; base += 1024) {
        const int a = base + t;
        bool pred = false;
        float ax = 0.f, ay = 0.f, az = 0.f, cut = 0.f;
        if (a < n) {
            ax = sx[a]; ay = sy[a]; az = sz[a]; cut = scut[a];
            const float ddx = fmaxf(fmaxf(lox - ax, ax - hix), 0.f);
            const float ddy = fmaxf(fmaxf(loy - ay, ay - hiy), 0.f);
            const float ddz = fmaxf(fmaxf(loz - az, az - hiz), 0.f);
            pred = fmaf(ddx, ddx, fmaf(ddy, ddy, ddz * ddz)) < cut * cut;
        }
        const unsigned long long m = __ballot(pred);
        if (l == 0) sCnt[w] = __popcll(m);
        __syncthreads();
        int ofs = runTot, tot = 0;
        #pragma unroll
        for (int w2 = 0; w2 < 16; ++w2) {
            const int c = sCnt[w2];
            if (w2 < w) ofs += c;
            tot += c;
        }
        if (pred) {
            const int o = ofs + __popcll(m & ((1ull << l) - 1ull));
            if (o < SBCAP) {
                segA[sb * SBCAP + o] = make_float4(ax, ay, az, cut);
                segB[sb * SBCAP + o] = make_float4(sb0[a], sb1[a], sb2[a], sb3[a]);
            }
        }
        runTot += tot;
        __syncthreads();
    }
    if (t == 0) counts[sb] = min(runTot, SBCAP);
}

// ================= Kernel B: refine superblock list + gather =====================
__global__ __launch_bounds__(256)
void density_kernel(const float4* __restrict__ segA,
                    const float4* __restrict__ segB,
                    const int* __restrict__ counts,
                    float* __restrict__ out)
{
    __shared__ __align__(16) unsigned char smem[16384];   // sA/sB, later sRed
    __shared__ int sCnt[4];
    float4* const sA = (float4*)smem;                     // [4*SEGCAP]
    float4* const sB = sA + 4 * SEGCAP;
    float (*const sRed)[64] = (float (*)[64])smem;        // [4*NC][64]

    const int t = threadIdx.x, w = t >> 6, l = t & 63;
    const int bz = blockIdx.x, by = blockIdx.y, bx = blockIdx.z;

    const float blox = bx * 2.0f, bhix = blox + 1.5f;
    const float bloy = by * 2.0f, bhiy = bloy + 1.5f;
    const float bloz = bz * 2.0f, bhiz = bloz + 1.5f;

    const int sb = ((bx >> 2) * 3 + (by >> 2)) * 3 + (bz >> 2);
    const int cnt_sb = counts[sb];
    const float4* const srcA = segA + sb * SBCAP;
    const float4* const srcB = segB + sb * SBCAP;

    // ---- wave-private refine of a contiguous quarter of the superblock list ----
    const int q = (cnt_sb + 3) >> 2;
    const int i0 = w * q, i1 = min(i0 + q, cnt_sb);
    int myCnt = 0;
    for (int base = i0; base < i1; base += 64) {
        const int idx = base + l;
        bool pred = false;
        float4 pA, pB;
        if (idx < i1) {
            pA = srcA[idx];
            pB = srcB[idx];
            const float ddx = fmaxf(fmaxf(blox - pA.x, pA.x - bhix), 0.f);
            const float ddy = fmaxf(fmaxf(bloy - pA.y, pA.y - bhiy), 0.f);
            const float ddz = fmaxf(fmaxf(bloz - pA.z, pA.z - bhiz), 0.f);
            pred = fmaf(ddx, ddx, fmaf(ddy, ddy, ddz * ddz)) < pA.w * pA.w;
        }
        const unsigned long long m = __ballot(pred);
        if (pred) {
            const int o = myCnt + __popcll(m & ((1ull << l) - 1ull));
            if (o < SEGCAP) { sA[w * SEGCAP + o] = pA; sB[w * SEGCAP + o] = pB; }
        }
        myCnt += __popcll(m);
    }
    if (l == 0) sCnt[w] = min(myCnt, SEGCAP);
    __syncthreads();

    const int c0 = sCnt[0], c1 = sCnt[1], c2 = sCnt[2], c3 = sCnt[3];

    // lane -> grid point (4x4x4 brick)
    const int tz = l & 3, ty = (l >> 2) & 3, tx = l >> 4;
    const float px = (bx * BR + tx) * 0.5f;
    const float py = (by * BR + ty) * 0.5f;
    const float pz = (bz * BR + tz) * 0.5f;

    float acc[NC];
    #pragma unroll
    for (int c = 0; c < NC; ++c) acc[c] = 0.0f;

    #pragma unroll 1
    for (int s = 0; s < 4; ++s) {
        const int cs = (s == 0) ? c0 : (s == 1) ? c1 : (s == 2) ? c2 : c3;
        const int segbase = s * SEGCAP;
        #pragma unroll 2
        for (int i = w; i < cs; i += 4) {
            const float4 A = sA[segbase + i];     // wave-uniform broadcast
            const float4 B = sB[segbase + i];
            const float dx = px - A.x;
            const float dy = py - A.y;
            const float dz = pz - A.z;
            const float d2 = fmaf(dx, dx, fmaf(dy, dy, dz * dz));
            const float cut2 = A.w * A.w;
            if (d2 < cut2) {
                const float r2 = cut2 * (4.0f / 9.0f);
                const float d  = sqrtf(d2);
                const float f1 = exp2f(B.x * d2);
                const float f2 = fmaf(B.y, d2, fmaf(-B.z, d, NINE_OVER_E2));
                const float val = (d2 < r2) ? f1 : f2;
                const int chan = __builtin_amdgcn_readfirstlane(__float_as_int(B.w));
                #pragma unroll
                for (int c = 0; c < NC; ++c)
                    if (chan & (1 << c)) acc[c] += val;   // scalar-branched
            }
        }
    }
    __syncthreads();   // gather done -> safe to overwrite sA/sB with sRed

    #pragma unroll
    for (int c = 0; c < NC; ++c) sRed[w * NC + c][l] = acc[c];
    __syncthreads();

    const int gx = bx * BR + tx, gy = by * BR + ty, gz = bz * BR + tz;
    const int pbase = (gx * NG + gy) * NG + gz;
    #pragma unroll
    for (int k = 0; k < 4; ++k) {
        const int c = w * 4 + k;
        const float s = sRed[0 * NC + c][l] + sRed[1 * NC + c][l] +
                        sRed[2 * NC + c][l] + sRed[3 * NC + c][l];
        out[c * NPTS + pbase] = s;
    }
}

// ================= Fallback (R3 path) for small ws / large natoms ================
__global__ void prep_kernel(const float* __restrict__ coords,
                            const int* __restrict__ ch_idx,
                            const int* __restrict__ fg,
                            float4* __restrict__ atomA,
                            float4* __restrict__ atomB, int natoms)
{
    const int i = blockIdx.x * blockDim.x + threadIdx.x;
    if (i >= natoms) return;
    const int ci = ch_idx[i], f = fg[i];
    const float r = c_vdw[ci];
    float b0, b1, b2; int mask;
    atom_params(ci, f, r, b0, b1, b2, mask);
    atomA[i] = make_float4(coords[3 * i], coords[3 * i + 1], coords[3 * i + 2], 1.5f * r);
    atomB[i] = make_float4(b0, b1, b2, __int_as_float(mask));
}

__global__ __launch_bounds__(256)
void density_scan_kernel(const float4* __restrict__ atomA,
                         const float4* __restrict__ atomB,
                         float* __restrict__ out, int natoms)
{
    __shared__ __align__(16) unsigned char smem[16384];
    __shared__ int sCnt[4];
    float4* const sA = (float4*)smem;
    float4* const sB = sA + 4 * SEGCAP;
    float (*const sRed)[64] = (float (*)[64])smem;

    const int t = threadIdx.x, w = t >> 6, l = t & 63;
    const int bz = blockIdx.x, by = blockIdx.y, bx = blockIdx.z;

    const float blox = bx * 2.0f, bhix = blox + 1.5f;
    const float bloy = by * 2.0f, bhiy = bloy + 1.5f;
    const float bloz = bz * 2.0f, bhiz = bloz + 1.5f;

    const int quarter = (natoms + 3) >> 2;
    const int a0 = w * quarter, a1 = min(a0 + quarter, natoms);
    int myCnt = 0;
    for (int base = a0; base < a1; base += 64) {
        const int a = base + l;
        bool pred = false; float4 pA;
        if (a < a1) {
            pA = atomA[a];
            const float ddx = fmaxf(fmaxf(blox - pA.x, pA.x - bhix), 0.f);
            const float ddy = fmaxf(fmaxf(bloy - pA.y, pA.y - bhiy), 0.f);
            const float ddz = fmaxf(fmaxf(bloz - pA.z, pA.z - bhiz), 0.f);
            pred = fmaf(ddx, ddx, fmaf(ddy, ddy, ddz * ddz)) < pA.w * pA.w;
        }
        const unsigned long long m = __ballot(pred);
        if (pred) {
            const int o = myCnt + __popcll(m & ((1ull << l) - 1ull));
            if (o < SEGCAP) { sA[w * SEGCAP + o] = pA; sB[w * SEGCAP + o] = atomB[a]; }
        }
        myCnt += __popcll(m);
    }
    if (l == 0) sCnt[w] = min(myCnt, SEGCAP);
    __syncthreads();

    const int c0 = sCnt[0], c1 = sCnt[1], c2 = sCnt[2], c3 = sCnt[3];
    const int tz = l & 3, ty = (l >> 2) & 3, tx = l >> 4;
    const float px = (bx * BR + tx) * 0.5f;
    const float py = (by * BR + ty) * 0.5f;
    const float pz = (bz * BR + tz) * 0.5f;

    float acc[NC];
    #pragma unroll
    for (int c = 0; c < NC; ++c) acc[c] = 0.0f;

    #pragma unroll 1
    for (int s = 0; s < 4; ++s) {
        const int cs = (s == 0) ? c0 : (s == 1) ? c1 : (s == 2) ? c2 : c3;
        const int segbase = s * SEGCAP;
        #pragma unroll 2
        for (int i = w; i < cs; i += 4) {
            const float4 A = sA[segbase + i];
            const float4 B = sB[segbase + i];
            const float dx = px - A.x, dy = py - A.y, dz = pz - A.z;
            const float d2 = fmaf(dx, dx, fmaf(dy, dy, dz * dz));
            const float cut2 = A.w * A.w;
            if (d2 < cut2) {
                const float r2 = cut2 * (4.0f / 9.0f);
                const float d  = sqrtf(d2);
                const float f1 = exp2f(B.x * d2);
                const float f2 = fmaf(B.y, d2, fmaf(-B.z, d, NINE_OVER_E2));
                const float val = (d2 < r2) ? f1 : f2;
                const int chan = __builtin_amdgcn_readfirstlane(__float_as_int(B.w));
                #pragma unroll
                for (int c = 0; c < NC; ++c)
                    if (chan & (1 << c)) acc[c] += val;
            }
        }
    }
    __syncthreads();
    #pragma unroll
    for (int c = 0; c < NC; ++c) sRed[w * NC + c][l] = acc[c];
    __syncthreads();

    const int gx = bx * BR + tx, gy = by * BR + ty, gz = bz * BR + tz;
    const int pbase = (gx * NG + gy) * NG + gz;
    #pragma unroll
    for (int k = 0; k < 4; ++k) {
        const int c = w * 4 + k;
        out[c * NPTS + pbase] = sRed[0 * NC + c][l] + sRed[1 * NC + c][l] +
                                sRed[2 * NC + c][l] + sRed[3 * NC + c][l];
    }
}

extern "C" void kernel_launch(void* const* d_in, const int* in_sizes, int n_in,
                              void* d_out, int out_size, void* d_ws, size_t ws_size,
                              hipStream_t stream) {
    (void)n_in; (void)out_size;
    const float* coords = (const float*)d_in[0];
    const int* ch = (const int*)d_in[1];
    const int* fgp = (const int*)d_in[2];
    float* out = (float*)d_out;
    const int natoms = in_sizes[0] / 3;

    const size_t need = 256 + 2ull * 27 * SBCAP * sizeof(float4);
    dim3 grid(NG / BR, NG / BR, NG / BR);   // (bz, by, bx) = 12^3

    if (natoms <= MAXATOMS && ws_size >= need) {
        int* counts = (int*)d_ws;
        float4* segA = (float4*)((char*)d_ws + 256);
        float4* segB = segA + 27 * SBCAP;
        build_kernel<<<27, 1024, 0, stream>>>(coords, ch, fgp, segA, segB, counts, natoms);
        density_kernel<<<grid, 256, 0, stream>>>(segA, segB, counts, out);
    } else {
        float4* atomA = (float4*)d_ws;
        float4* atomB = atomA + natoms;
        prep_kernel<<<(natoms + 255) / 256, 256, 0, stream>>>(coords, ch, fgp, atomA, atomB, natoms);
        density_scan_kernel<<<grid, 256, 0, stream>>>(atomA, atomB, out, natoms);
    }
}